// Round 1
// baseline (734.758 us; speedup 1.0000x reference)
//
#include <hip/hip_runtime.h>
#include <math.h>

typedef float v4f __attribute__((ext_vector_type(4)));
typedef short v8s __attribute__((ext_vector_type(8)));

#define NBATCH 4096
#define NT 64
#define HD 256
#define UD 128
#define ZD 16
#define AD 64
#define LRSCALE 0.25f

// output offsets (floats) in d_out: c, z_next, attn, q, k, v
#define OFF_C    0UL
#define OFF_ZN   33554432UL
#define OFF_ATTN 37748736UL
#define OFF_Q    54525952UL
#define OFF_K    71303168UL
#define OFF_V    88080384UL

// d_ws layout in shorts (bf16, pre-transposed by prep_weights):
//  WT1 [48][288] @0      (row n = output col; n<4: qd_down col n over K=[h|z](272);
//                         n in 16..47: gate/cand weight h,z rows)
//  WT2 [16][128] @13824  (n<4: kd_down, n in 4..7: vd_down)
//  WoT [128][64] @15872  (WoT[e][d] = sum_r od_down[d][r]*od_up[r][e] * SCALE)
//  WcT [32][128] @24064  (gate/cand weight c-rows 272..399, transposed)
#define WS_WT2 13824
#define WS_WOT 15872
#define WS_WCT 24064
#define WS_TOTAL 28160  // shorts = 56320 bytes

__device__ __forceinline__ short f2bf(float x) {
  unsigned u = __float_as_uint(x);
  u = (u + 0x7fffu + ((u >> 16) & 1u)) >> 16;  // RNE
  return (short)u;
}
__device__ __forceinline__ v8s ld8(const short* p) { return *(const v8s*)p; }
__device__ __forceinline__ v8s pack8(v4f x0, v4f x1) {
  v8s a;
  a[0] = f2bf(x0.x); a[1] = f2bf(x0.y); a[2] = f2bf(x0.z); a[3] = f2bf(x0.w);
  a[4] = f2bf(x1.x); a[5] = f2bf(x1.y); a[6] = f2bf(x1.z); a[7] = f2bf(x1.w);
  return a;
}

// ---------------- setup kernel: run once per launch, writes bf16 weights ----------------
__global__ void prep_weights(
    const float* __restrict__ qd_down, const float* __restrict__ kd_down,
    const float* __restrict__ vd_down, const float* __restrict__ od_down,
    const float* __restrict__ od_up, const float* __restrict__ ug_w,
    const float* __restrict__ cand_w, short* __restrict__ ws)
{
  int idx = blockIdx.x * 256 + threadIdx.x;
  if (idx < WS_WT2) {
    // WT1 [48][288]
    int n = idx / 288, k = idx - n * 288;
    float val = 0.f;
    if (n < 4) {
      if (k < 272) val = qd_down[k * 4 + n];      // q_in=[h,z] matches qd_down rows
    } else if (n >= 16) {
      const float* W = (n < 32) ? ug_w : cand_w;  // mix=[z,h,c]: z rows 0..15, h rows 16..271
      int o = (n < 32) ? (n - 16) : (n - 32);
      if (k < 256) val = W[(16 + k) * 16 + o];    // h dims
      else if (k < 272) val = W[(k - 256) * 16 + o];  // z dims
    }
    ws[idx] = f2bf(val);
  } else if (idx < WS_WOT) {
    // WT2 [16][128]
    int j = idx - WS_WT2;
    int n = j >> 7, k = j & 127;
    float val = 0.f;
    if (n < 4) val = kd_down[k * 4 + n];
    else if (n < 8) val = vd_down[k * 4 + (n - 4)];
    ws[idx] = f2bf(val);
  } else if (idx < WS_WCT) {
    // WoT [128][64]
    int j = idx - WS_WOT;
    int e2 = j >> 6, d = j & 63;
    float a = od_down[d * 4 + 0] * od_up[e2] + od_down[d * 4 + 1] * od_up[128 + e2]
            + od_down[d * 4 + 2] * od_up[256 + e2] + od_down[d * 4 + 3] * od_up[384 + e2];
    ws[idx] = f2bf(a * LRSCALE);
  } else if (idx < WS_TOTAL) {
    // WcT [32][128]
    int j = idx - WS_WCT;
    int o = j >> 7, e2 = j & 127;
    const float* W = (o < 16) ? ug_w : cand_w;
    ws[idx] = f2bf(W[(272 + e2) * 16 + (o & 15)]);
  }
}

// ---------------- main kernel: one workgroup per batch, 256 threads = 4 waves ----------------
// LDS scr overlay (36864 B):
//  P3-P4: q_s[64][72] @0, k_s @9216, vT @18432 (bf16, 9216 B each)
//  P4:    attnF f32[64][66] @0 (16896 B, over q_s/k_s after GEMM3+barrier), attnB bf16[64][72] @27648
//  P5:    clB[64][72] @0 (over attnF, dead after softmax barrier)
//  P6-P7: cB[64][136] @9216 (17408 B, over attnF-tail/vT, dead after P5 barrier)
__global__ __launch_bounds__(256, 3)
void memetic_fused(
    const float* __restrict__ hg, const float* __restrict__ ug2,
    const float* __restrict__ zg,
    const float* __restrict__ qd_up, const float* __restrict__ kd_up,
    const float* __restrict__ vd_up,
    const float* __restrict__ ug_b, const float* __restrict__ cand_b,
    const float* __restrict__ eta_logit,
    const short* __restrict__ wsw,
    float* __restrict__ c_o, float* __restrict__ zn_o,
    float* __restrict__ attn_o, float* __restrict__ q_o,
    float* __restrict__ k_o, float* __restrict__ v_o)
{
  __shared__ float g1out[NT * 33];  // gate_pre[0..15], cand_pre[16..31]
  __shared__ float qkv4[NT * 13];   // qd4[0..3], kd4[4..7], vd4[8..11]
  __shared__ char scr[36864];

  const int b = blockIdx.x;
  const int tid = threadIdx.x;
  const int lane = tid & 63;
  const int wv = tid >> 6;      // wave 0..3
  const int quad = lane >> 4;   // 0..3
  const int l16 = lane & 15;

  const short* WT1g = wsw;            // [48][288]
  const short* WT2g = wsw + WS_WT2;   // [16][128]
  const short* WOTg = wsw + WS_WOT;   // [128][64]
  const short* WCTg = wsw + WS_WCT;   // [32][128]

  // This wave's token rows for GEMM1/GEMM2 M-tiles
  const int tok = wv * 16 + l16;
  const float* hrow = hg + ((size_t)b * NT + tok) * HD;
  const float* urow = ug2 + ((size_t)b * NT + tok) * UD;
  const float* zrow = zg + ((size_t)b * NT + tok) * ZD;

  // ---------- P1: GEMM1  A=[h|z] (K=272 pad 288), N=48: [qd4(4)+pad | gate(16) | cand(16)] ----------
  // A and B fragments loaded DIRECTLY from global — no LDS staging, no barriers.
  v4f acc1[3];
  for (int i = 0; i < 3; ++i) acc1[i] = (v4f){0.f, 0.f, 0.f, 0.f};
#pragma unroll
  for (int kc = 0; kc < 9; ++kc) {
    v8s a;
    if (kc < 8) {
      v4f x0 = *(const v4f*)(hrow + kc * 32 + quad * 8);
      v4f x1 = *(const v4f*)(hrow + kc * 32 + quad * 8 + 4);
      a = pack8(x0, x1);
    } else if (quad < 2) {  // k=256..271 -> z[0..15]; quads 2,3 are weight-zero padding
      v4f x0 = *(const v4f*)(zrow + quad * 8);
      v4f x1 = *(const v4f*)(zrow + quad * 8 + 4);
      a = pack8(x0, x1);
    } else {
      a = (v8s){0, 0, 0, 0, 0, 0, 0, 0};
    }
    const short* wrow = WT1g + kc * 32 + quad * 8;
#pragma unroll
    for (int nt = 0; nt < 3; ++nt) {
      v8s bb = ld8(wrow + (nt * 16 + l16) * 288);  // B[k][n] via BT[n][k], L2-hot
      acc1[nt] = __builtin_amdgcn_mfma_f32_16x16x32_bf16(a, bb, acc1[nt], 0, 0, 0);
    }
  }

  // ---------- P2: GEMM2  A=u (K=128), N=16: [kd4(4) vd4(4) pad(8)] ----------
  v4f acc2 = (v4f){0.f, 0.f, 0.f, 0.f};
#pragma unroll
  for (int kc = 0; kc < 4; ++kc) {
    v4f x0 = *(const v4f*)(urow + kc * 32 + quad * 8);
    v4f x1 = *(const v4f*)(urow + kc * 32 + quad * 8 + 4);
    v8s a = pack8(x0, x1);
    v8s bb = ld8(WT2g + l16 * 128 + kc * 32 + quad * 8);
    acc2 = __builtin_amdgcn_mfma_f32_16x16x32_bf16(a, bb, acc2, 0, 0, 0);
  }

  // Epilogue: C/D layout col=l16, row=quad*4+r; wave's M-tile = wv
  if (l16 < 4) {
#pragma unroll
    for (int r = 0; r < 4; ++r)
      qkv4[(wv * 16 + quad * 4 + r) * 13 + l16] = acc1[0][r];
  }
#pragma unroll
  for (int r = 0; r < 4; ++r) {
    int row = wv * 16 + quad * 4 + r;
    g1out[row * 33 + l16] = acc1[1][r];
    g1out[row * 33 + 16 + l16] = acc1[2][r];
  }
  if (l16 < 8) {
#pragma unroll
    for (int r = 0; r < 4; ++r)
      qkv4[(wv * 16 + quad * 4 + r) * 13 + 4 + l16] = acc2[r];
  }
  __syncthreads();  // barrier 1

  // ---------- P3: expand q,k,v = rank4 @ up * SCALE; write global f32 + LDS bf16 ----------
  {
    short* q_s = (short*)scr;
    short* k_s = (short*)(scr + 9216);
    short* vT = (short*)(scr + 18432);
    float qup[4], kup[4], vup[4];
#pragma unroll
    for (int r = 0; r < 4; ++r) {
      qup[r] = qd_up[r * AD + lane];
      kup[r] = kd_up[r * AD + lane];
      vup[r] = vd_up[r * AD + lane];
    }
    for (int i = 0; i < 16; ++i) {
      int t = wv * 16 + i;
      const float* p4 = qkv4 + t * 13;
      float qv = LRSCALE * (p4[0] * qup[0] + p4[1] * qup[1] + p4[2] * qup[2] + p4[3] * qup[3]);
      float kv = LRSCALE * (p4[4] * kup[0] + p4[5] * kup[1] + p4[6] * kup[2] + p4[7] * kup[3]);
      float vv = LRSCALE * (p4[8] * vup[0] + p4[9] * vup[1] + p4[10] * vup[2] + p4[11] * vup[3]);
      size_t go = ((size_t)b * NT + t) * AD + lane;
      q_o[go] = qv; k_o[go] = kv; v_o[go] = vv;
      q_s[t * 72 + lane] = f2bf(qv);
      k_s[t * 72 + lane] = f2bf(kv);
      vT[lane * 72 + t] = f2bf(vv);   // transposed for PV B-operand
    }
  }
  __syncthreads();  // barrier 2

  // ---------- P4: scores = q @ k^T / 8, diag mask, softmax ----------
  v4f acc3[4];
  for (int i = 0; i < 4; ++i) acc3[i] = (v4f){0.f, 0.f, 0.f, 0.f};
  {
    short* q_s = (short*)scr;
    short* k_s = (short*)(scr + 9216);
#pragma unroll
    for (int kc = 0; kc < 2; ++kc) {
      v8s bb = ld8(k_s + (wv * 16 + l16) * 72 + kc * 32 + quad * 8);  // B[d][m]=k[m][d]
#pragma unroll
      for (int mt = 0; mt < 4; ++mt) {
        v8s a = ld8(q_s + (mt * 16 + l16) * 72 + kc * 32 + quad * 8);
        acc3[mt] = __builtin_amdgcn_mfma_f32_16x16x32_bf16(a, bb, acc3[mt], 0, 0, 0);
      }
    }
  }
  __syncthreads();  // barrier 3 (q_s/k_s reads done before attnF overlay)
  {
    float* attnF = (float*)scr;  // [64][66]
#pragma unroll
    for (int mt = 0; mt < 4; ++mt)
#pragma unroll
      for (int r = 0; r < 4; ++r) {
        int row = mt * 16 + quad * 4 + r;
        int col = wv * 16 + l16;
        float s = acc3[mt][r] * 0.125f;
        attnF[row * 66 + col] = (row == col) ? -INFINITY : s;
      }
  }
  __syncthreads();  // barrier 4
  {
    float* attnF = (float*)scr;
    short* attnB = (short*)(scr + 27648);
    int n = tid >> 2, p = tid & 3;
    float e[16];
    float mx = -INFINITY;
    const float* rp = attnF + n * 66 + p * 16;
#pragma unroll
    for (int i = 0; i < 16; ++i) { e[i] = rp[i]; mx = fmaxf(mx, e[i]); }
    mx = fmaxf(mx, __shfl_xor(mx, 1));
    mx = fmaxf(mx, __shfl_xor(mx, 2));
    float s = 0.f;
#pragma unroll
    for (int i = 0; i < 16; ++i) { float ee = __expf(e[i] - mx); e[i] = ee; s += ee; }
    s += __shfl_xor(s, 1);
    s += __shfl_xor(s, 2);
    float inv = 1.f / s;
    size_t gb = ((size_t)b * NT + n) * NT + p * 16;
#pragma unroll
    for (int i = 0; i < 16; ++i) {
      float av = e[i] * inv;          // diag: exp(-inf)=0 -> exact 0
      attn_o[gb + i] = av;
      attnB[n * 72 + p * 16 + i] = f2bf(av);
    }
  }
  __syncthreads();  // barrier 5

  // ---------- P5: c_latent = attn @ v ----------
  v4f acc4[4];
  for (int i = 0; i < 4; ++i) acc4[i] = (v4f){0.f, 0.f, 0.f, 0.f};
  {
    short* attnB = (short*)(scr + 27648);
    short* vT = (short*)(scr + 18432);
#pragma unroll
    for (int kc = 0; kc < 2; ++kc) {
      v8s bb = ld8(vT + (wv * 16 + l16) * 72 + kc * 32 + quad * 8);  // B[m][d]=vT[d][m]
#pragma unroll
      for (int mt = 0; mt < 4; ++mt) {
        v8s a = ld8(attnB + (mt * 16 + l16) * 72 + kc * 32 + quad * 8);
        acc4[mt] = __builtin_amdgcn_mfma_f32_16x16x32_bf16(a, bb, acc4[mt], 0, 0, 0);
      }
    }
  }
  {
    short* clB = (short*)scr;  // [64][72] @0, over attnF (dead since barrier 5)
#pragma unroll
    for (int mt = 0; mt < 4; ++mt)
#pragma unroll
      for (int r = 0; r < 4; ++r)
        clB[(mt * 16 + quad * 4 + r) * 72 + wv * 16 + l16] = f2bf(acc4[mt][r]);
  }
  __syncthreads();  // barrier 6 (all P5 reads done; clB complete)

  // ---------- P6: c = c_latent @ WoT (pre-fused od_down@od_up*SCALE, from global) ----------
  v4f acc5[4][2];
  for (int i = 0; i < 4; ++i)
    for (int j = 0; j < 2; ++j) acc5[i][j] = (v4f){0.f, 0.f, 0.f, 0.f};
  {
    short* clB = (short*)scr;
#pragma unroll
    for (int kc = 0; kc < 2; ++kc)
#pragma unroll
      for (int mt = 0; mt < 4; ++mt) {
        v8s a = ld8(clB + (mt * 16 + l16) * 72 + kc * 32 + quad * 8);
#pragma unroll
        for (int j = 0; j < 2; ++j) {
          v8s bb = ld8(WOTg + ((wv + 4 * j) * 16 + l16) * 64 + kc * 32 + quad * 8);
          acc5[mt][j] = __builtin_amdgcn_mfma_f32_16x16x32_bf16(a, bb, acc5[mt][j], 0, 0, 0);
        }
      }
  }
  {
    short* cB = (short*)(scr + 9216);  // [64][136], over dead attnF-tail/vT
#pragma unroll
    for (int mt = 0; mt < 4; ++mt)
#pragma unroll
      for (int j = 0; j < 2; ++j)
#pragma unroll
        for (int r = 0; r < 4; ++r) {
          int row = mt * 16 + quad * 4 + r;
          int e2 = (wv + 4 * j) * 16 + l16;
          float val = acc5[mt][j][r];
          c_o[((size_t)b * NT + row) * UD + e2] = val;
          cB[row * 136 + e2] = f2bf(val);
        }
  }
  __syncthreads();  // barrier 7

  // ---------- P7: gate/cand c-part: c @ W[272:400] (WcT from global) added into g1out ----------
  v4f acc6[2];
  for (int i = 0; i < 2; ++i) acc6[i] = (v4f){0.f, 0.f, 0.f, 0.f};
  {
    short* cB = (short*)(scr + 9216);
#pragma unroll
    for (int kc = 0; kc < 4; ++kc) {
      v8s a = ld8(cB + (wv * 16 + l16) * 136 + kc * 32 + quad * 8);
#pragma unroll
      for (int nt = 0; nt < 2; ++nt) {
        v8s bb = ld8(WCTg + (nt * 16 + l16) * 128 + kc * 32 + quad * 8);
        acc6[nt] = __builtin_amdgcn_mfma_f32_16x16x32_bf16(a, bb, acc6[nt], 0, 0, 0);
      }
    }
  }
#pragma unroll
  for (int nt = 0; nt < 2; ++nt)
#pragma unroll
    for (int r = 0; r < 4; ++r) {
      int row = wv * 16 + quad * 4 + r;
      g1out[row * 33 + nt * 16 + l16] += acc6[nt][r];  // same thread as P1 write — no race
    }
  __syncthreads();  // barrier 8

  // ---------- P8: gated update + layernorm ----------
  if (tid < NT) {
    const int t = tid;
    const float* zr = zg + ((size_t)b * NT + t) * ZD;
    float eta = 1.f / (1.f + __expf(-eta_logit[0]));
    float x[16];
    float mean = 0.f;
#pragma unroll
    for (int o = 0; o < 16; ++o) {
      float gpre = g1out[t * 33 + o] + ug_b[o];
      float cpre = g1out[t * 33 + 16 + o] + cand_b[o];
      float gate = 1.f / (1.f + __expf(-gpre));
      float prop = tanhf(cpre);
      float eg = eta * gate;
      float xv = (1.f - eg) * zr[o] + eg * prop;
      x[o] = xv;
      mean += xv;
    }
    mean *= (1.f / 16.f);
    float var = 0.f;
#pragma unroll
    for (int o = 0; o < 16; ++o) { float d0 = x[o] - mean; var += d0 * d0; }
    var *= (1.f / 16.f);
    float rs = rsqrtf(var + 1e-5f);
#pragma unroll
    for (int o = 0; o < 16; ++o)
      zn_o[((size_t)b * NT + t) * ZD + o] = (x[o] - mean) * rs;
  }
}

extern "C" void kernel_launch(void* const* d_in, const int* in_sizes, int n_in,
                              void* d_out, int out_size, void* d_ws, size_t ws_size,
                              hipStream_t stream) {
  const float* h = (const float*)d_in[0];
  const float* u = (const float*)d_in[1];
  const float* z = (const float*)d_in[2];
  const float* qd_down = (const float*)d_in[3];
  const float* qd_up = (const float*)d_in[4];
  const float* kd_down = (const float*)d_in[5];
  const float* kd_up = (const float*)d_in[6];
  const float* vd_down = (const float*)d_in[7];
  const float* vd_up = (const float*)d_in[8];
  const float* od_down = (const float*)d_in[9];
  const float* od_up = (const float*)d_in[10];
  const float* ug_w = (const float*)d_in[11];
  const float* ug_b = (const float*)d_in[12];
  const float* cand_w = (const float*)d_in[13];
  const float* cand_b = (const float*)d_in[14];
  const float* eta_logit = (const float*)d_in[15];
  float* out = (float*)d_out;
  short* ws = (short*)d_ws;

  // Stage 1: pre-transpose/convert all GEMM B-operand weights once (56 KB, L2-resident).
  prep_weights<<<(WS_TOTAL + 255) / 256, 256, 0, stream>>>(
      qd_down, kd_down, vd_down, od_down, od_up, ug_w, cand_w, ws);

  // Stage 2: fused main kernel, one block per batch.
  memetic_fused<<<NBATCH, 256, 0, stream>>>(
      h, u, z, qd_up, kd_up, vd_up, ug_b, cand_b, eta_logit, ws,
      out + OFF_C, out + OFF_ZN, out + OFF_ATTN,
      out + OFF_Q, out + OFF_K, out + OFF_V);
}